// Round 12
// baseline (158.453 us; speedup 1.0000x reference)
//
#include <hip/hip_runtime.h>

// Problem constants
#define D    128      // d+1
#define DM   127      // d
#define NP1  1024     // N+1
#define B    8
#define H    8
#define NL   4
#define DD   (D*D)

typedef __attribute__((ext_vector_type(8))) __bf16 bf16x8;
typedef __attribute__((ext_vector_type(8))) unsigned short ushort8;
typedef __attribute__((ext_vector_type(4))) unsigned short ushort4v;
typedef __attribute__((ext_vector_type(4))) float f32x4;

// Workspace layout (float offsets), ~11.7 MB
#define WS_GP   0                           // [B][8][DD] f32 Gram partials
#define WS_SPT  (WS_GP + B*8*DD)            // [2][B][H][DD] bf16 S_h^T partials (ping-pong)
#define WS_QB   (WS_SPT + 2*B*H*DD/2)       // [NL][H][DD] bf16 Qf (1/N folded), swz
#define WS_PB   (WS_QB + NL*H*DD/2)         // [NL][H][DD] bf16 Pf (corner 1), swz
#define WS_GBF  (WS_PB + NL*H*DD/2)         // [2][B][DD] bf16 G swz (ping-pong)
#define WS_GF   (WS_GBF + 2*B*DD/2)         // [2][B][DD] f32 G (transposed; symmetric)
#define WS_SRM  (WS_GF + 2*B*DD)            // [B][DD] bf16 S_0 row-major swz
#define WS_ST1  (WS_SRM + B*DD/2)           // [B][DD] bf16 S_1^T swz
#define WS_ST2  (WS_ST1 + B*DD/2)           // [B][DD] bf16 S_2^T swz

__device__ __forceinline__ void async16(const void* g, void* l)
{
    __builtin_amdgcn_global_load_lds(
        (const __attribute__((address_space(1))) void*)g,
        (__attribute__((address_space(3))) void*)l,
        16, 0, 0);
}
__device__ __forceinline__ unsigned short f2bf(float f)
{
    unsigned int u = __float_as_uint(f);
    u += 0x7fffu + ((u >> 16) & 1u);
    return (unsigned short)(u >> 16);
}
__device__ __forceinline__ float bf2f(unsigned short v)
{
    return __uint_as_float((unsigned int)v << 16);
}
__device__ __forceinline__ int SW(int row, int col)   // bf16 [*][128] swizzle
{
    return row * 128 + (col ^ ((row & 7) << 3));
}
__device__ __forceinline__ bf16x8 fragAB(const unsigned short* Lb, int row0, int k0, int lane)
{
    const int r = row0 + (lane & 15);
    const int c = (k0 + ((lane >> 4) << 3)) ^ ((r & 7) << 3);
    union { ushort8 u; bf16x8 b; } U;
    U.u = *(const ushort8*)&Lb[r * 128 + c];
    return U.b;
}
__device__ __forceinline__ ushort4v packbf(f32x4 a)
{
    ushort4v v;
    v[0] = f2bf(a[0]); v[1] = f2bf(a[1]); v[2] = f2bf(a[2]); v[3] = f2bf(a[3]);
    return v;
}
#define MFMA(a, b, c) __builtin_amdgcn_mfma_f32_16x16x32_bf16((a), (b), (c), 0, 0, 0)

// ---------------------------------------------------------------------------
// pg: merged [gp: chunk Grams of Z0 via MFMA (blocks 0..63)] +
//            [prep: params -> bf16 swz (blocks 64..191)]. grid 192 x 256.
// Both bodies verbatim-proven (rounds 9/11).
// ---------------------------------------------------------------------------
__global__ __launch_bounds__(256) void pg_kernel(
    const float* __restrict__ Z, float* __restrict__ Gp,
    const float* __restrict__ ap, unsigned short* __restrict__ Qb,
    unsigned short* __restrict__ Pb)
{
    const int t = threadIdx.x;
    __shared__ __align__(16) float Zs[128 * 128];          // 64 KB
    __shared__ __align__(16) unsigned short Zt[128 * 128]; // 32 KB

    if (blockIdx.x < 64) {
        const int c = blockIdx.x & 7, b = blockIdx.x >> 3;
        const int lane = t & 63, w = t >> 6;

        const float* src = Z + ((size_t)b * NP1 + c * 128) * D;
        #pragma unroll
        for (int i = 0; i < 16; ++i)
            async16(src + (t + 256 * i) * 4, Zs + (t + 256 * i) * 4);
        __syncthreads();

        {
            const int d = t >> 1, half = t & 1;
            const int sft = (d & 7) << 3;
            #pragma unroll 4
            for (int tp = 0; tp < 32; ++tp) {
                const int tk = ((tp + d) & 31) * 2 + half * 64;
                float v0 = Zs[tk * 128 + d];
                float v1 = Zs[(tk + 1) * 128 + d];
                if (c == 7 && tk == 126) v1 = 0.f;   // key mask: token 1023
                ((unsigned int*)Zt)[(d * 128 + (tk ^ sft)) >> 1] =
                    (unsigned int)f2bf(v0) | ((unsigned int)f2bf(v1) << 16);
            }
        }
        __syncthreads();

        f32x4 acc[2][8] = {};
        #pragma unroll
        for (int k0 = 0; k0 < 128; k0 += 32) {
            const bf16x8 a0 = fragAB(Zt, (w * 2 + 0) * 16, k0, lane);
            const bf16x8 a1 = fragAB(Zt, (w * 2 + 1) * 16, k0, lane);
            #pragma unroll
            for (int nt = 0; nt < 8; ++nt) {
                const bf16x8 bb = fragAB(Zt, nt * 16, k0, lane);
                acc[0][nt] = MFMA(a0, bb, acc[0][nt]);
                acc[1][nt] = MFMA(a1, bb, acc[1][nt]);
            }
        }
        float* Gb = Gp + ((size_t)(b * 8 + c)) * DD;
        #pragma unroll
        for (int m = 0; m < 2; ++m) {
            const int rg = (w * 2 + m) * 16 + ((lane >> 4) << 2);
            #pragma unroll
            for (int nt = 0; nt < 8; ++nt) {
                const int cg = nt * 16 + (lane & 15);
                *(f32x4*)&Gb[cg * 128 + rg] = acc[m][nt];   // transposed (symmetric)
            }
        }
    } else {
        const int pid = blockIdx.x - 64;   // 0..127
        const float inv = 1.0f / 1023.0f;
        #pragma unroll
        for (int e = 0; e < 16; ++e) {
            const int p  = pid * 4096 + e * 256 + t;   // 0 .. 2^19-1
            const int c  = (p & 63) * 2;
            const int r  = (p >> 6) & 127;
            const int h  = (p >> 13) & 7;
            const int isP = (p >> 16) & 1;
            const int l  = (p >> 17) & 3;
            const float* apl = ap + ((size_t)(l * H + h) * 2 + (isP ? 0 : 1)) * DM * DM;
            float v0, v1;
            if (!isP) {
                v0 = (r < DM && c     < DM) ? apl[r * DM + c] * inv     : 0.f;
                v1 = (r < DM && c + 1 < DM) ? apl[r * DM + c + 1] * inv : 0.f;
            } else {
                v0 = (r < DM && c     < DM) ? apl[r * DM + c]     : 0.f;
                v1 = (r < DM && c + 1 < DM) ? apl[r * DM + c + 1]
                     : ((r == DM && c + 1 == DM) ? 1.f : 0.f);
            }
            unsigned short* base = (isP ? Pb : Qb) + (size_t)(l * H + h) * DD;
            const int el = SW(r, c);
            ((unsigned int*)base)[el >> 1] =
                (unsigned int)f2bf(v0) | ((unsigned int)f2bf(v1) << 16);
        }
    }
}

// ---------------------------------------------------------------------------
// gred: G0 = sum_c Gp -> bf16 swz + f32. grid (16, B) x 256. (proven)
// ---------------------------------------------------------------------------
__global__ __launch_bounds__(256) void gred_kernel(
    const float* __restrict__ Gp, unsigned short* __restrict__ Gbf,
    float* __restrict__ Gf)
{
    const int b = blockIdx.y;
    const int idx4 = blockIdx.x * 256 + threadIdx.x;
    float4 sum = make_float4(0.f, 0.f, 0.f, 0.f);
    #pragma unroll
    for (int c = 0; c < 8; ++c) {
        const float4 v = ((const float4*)Gp)[(size_t)(b * 8 + c) * 4096 + idx4];
        sum.x += v.x; sum.y += v.y; sum.z += v.z; sum.w += v.w;
    }
    ((float4*)Gf)[(size_t)b * 4096 + idx4] = sum;
    const int row = idx4 >> 5;
    const int n0  = (idx4 & 31) * 4;
    const int el  = SW(row, n0);
    unsigned int* dst = (unsigned int*)(Gbf + (size_t)b * DD);
    dst[(el >> 1) + 0] = (unsigned int)f2bf(sum.x) | ((unsigned int)f2bf(sum.y) << 16);
    dst[(el >> 1) + 1] = (unsigned int)f2bf(sum.z) | ((unsigned int)f2bf(sum.w) << 16);
}

// ---------------------------------------------------------------------------
// heads0: Spt0[b][h] = (Qf_h G0 Pf_h^T)^T. grid (H, B) x 256. (r11 verbatim)
// ---------------------------------------------------------------------------
__global__ __launch_bounds__(256) void heads0_kernel(
    const unsigned short* __restrict__ Qbl, const unsigned short* __restrict__ Pbl,
    const unsigned short* __restrict__ Gbf, unsigned short* __restrict__ Spt)
{
    const int h = blockIdx.x, b = blockIdx.y;
    const int t = threadIdx.x, lane = t & 63, w = t >> 6;

    __shared__ __align__(16) unsigned short Gs[DD];
    __shared__ __align__(16) unsigned short Ps[DD];
    __shared__ __align__(16) unsigned short Qs[DD];
    __shared__ __align__(16) unsigned short Ub[DD];

    const unsigned short* gsrc = Gbf + (size_t)b * DD;
    #pragma unroll
    for (int i = 0; i < 8; ++i)
        async16((const char*)gsrc + (t + 256 * i) * 16, (char*)Gs + (t + 256 * i) * 16);
    const unsigned short* psrc = Pbl + (size_t)h * DD;
    #pragma unroll
    for (int i = 0; i < 8; ++i)
        async16((const char*)psrc + (t + 256 * i) * 16, (char*)Ps + (t + 256 * i) * 16);
    const unsigned short* qsrc = Qbl + (size_t)h * DD;
    #pragma unroll
    for (int i = 0; i < 8; ++i)
        async16((const char*)qsrc + (t + 256 * i) * 16, (char*)Qs + (t + 256 * i) * 16);

    asm volatile("s_waitcnt vmcnt(8)" ::: "memory");
    __builtin_amdgcn_s_barrier();
    asm volatile("" ::: "memory");

    f32x4 u[2][8] = {};
    #pragma unroll
    for (int k0 = 0; k0 < 128; k0 += 32) {
        const bf16x8 a0 = fragAB(Gs, (w * 2 + 0) * 16, k0, lane);
        const bf16x8 a1 = fragAB(Gs, (w * 2 + 1) * 16, k0, lane);
        #pragma unroll
        for (int i = 0; i < 8; ++i) {
            const bf16x8 bb = fragAB(Ps, i * 16, k0, lane);
            u[0][i] = MFMA(a0, bb, u[0][i]);
            u[1][i] = MFMA(a1, bb, u[1][i]);
        }
    }
    #pragma unroll
    for (int m = 0; m < 2; ++m) {
        const int rg0 = (w * 2 + m) * 16 + ((lane >> 4) << 2);
        #pragma unroll
        for (int i = 0; i < 8; ++i) {
            const int cg = i * 16 + (lane & 15);
            *(ushort4v*)&Ub[SW(cg, rg0)] = packbf(u[m][i]);
        }
    }
    __syncthreads();

    f32x4 sv[2][8] = {};
    #pragma unroll
    for (int k0 = 0; k0 < 128; k0 += 32) {
        const bf16x8 a0 = fragAB(Qs, (w * 2 + 0) * 16, k0, lane);
        const bf16x8 a1 = fragAB(Qs, (w * 2 + 1) * 16, k0, lane);
        #pragma unroll
        for (int i = 0; i < 8; ++i) {
            const bf16x8 bb = fragAB(Ub, i * 16, k0, lane);
            sv[0][i] = MFMA(a0, bb, sv[0][i]);
            sv[1][i] = MFMA(a1, bb, sv[1][i]);
        }
    }
    unsigned short* dst = Spt + (size_t)(b * H + h) * DD;
    #pragma unroll
    for (int m = 0; m < 2; ++m) {
        const int rg0 = (w * 2 + m) * 16 + ((lane >> 4) << 2);
        #pragma unroll
        for (int i = 0; i < 8; ++i) {
            const int cg = i * 16 + (lane & 15);
            *(ushort4v*)&dst[SW(cg, rg0)] = packbf(sv[m][i]);
        }
    }
}

// ---------------------------------------------------------------------------
// headsu (layers 1..3): per block: [stream-reduce Spt_{l-1}; G-update (a)(b)
// redundantly; head-h matmuls with G_l]. h==0 stores G_l and reduced-S.
// grid (H, B) x 256. LDS = Gs 32 | SQ 32 (Sts then Qs) | Ps 32 | XU 32 = 128 KB.
// ---------------------------------------------------------------------------
__global__ __launch_bounds__(256) void headsu_kernel(
    const unsigned short* __restrict__ Qbl, const unsigned short* __restrict__ Pbl,
    const unsigned short* __restrict__ Gbf_in, const float* __restrict__ Gf_in,
    unsigned short* __restrict__ Gbf_out, float* __restrict__ Gf_out,
    const unsigned short* __restrict__ Spt_in, unsigned short* __restrict__ Spt_out,
    unsigned short* __restrict__ StOut, unsigned short* __restrict__ SrmOut,
    int writeSt, int writeSrm)
{
    const int h = blockIdx.x, b = blockIdx.y;
    const int t = threadIdx.x, lane = t & 63, w = t >> 6;

    __shared__ __align__(16) unsigned short Gs[DD];   // G_{l-1} then G_l
    __shared__ __align__(16) unsigned short SQ[DD];   // Sts (S^T), later Qs
    __shared__ __align__(16) unsigned short Ps[DD];
    __shared__ __align__(16) unsigned short XU[DD];   // Xb then Ub

    const unsigned short* gsrc = Gbf_in + (size_t)b * DD;
    #pragma unroll
    for (int i = 0; i < 8; ++i)
        async16((const char*)gsrc + (t + 256 * i) * 16, (char*)Gs + (t + 256 * i) * 16);
    const unsigned short* psrc = Pbl + (size_t)h * DD;
    #pragma unroll
    for (int i = 0; i < 8; ++i)
        async16((const char*)psrc + (t + 256 * i) * 16, (char*)Ps + (t + 256 * i) * 16);

    // stream-reduce Spt_{l-1} -> Sts (fp32 acc); h==0 stores St/Srm globals
    {
        const unsigned short* sp0 = Spt_in + (size_t)b * H * DD;
        #pragma unroll 2
        for (int i = 0; i < 8; ++i) {
            const int ch = t + 256 * i;   // ushort8 chunk id
            float a[8] = {0.f, 0.f, 0.f, 0.f, 0.f, 0.f, 0.f, 0.f};
            #pragma unroll
            for (int hh = 0; hh < 8; ++hh) {
                const ushort8 uu = *(const ushort8*)&sp0[(size_t)hh * DD + ch * 8];
                #pragma unroll
                for (int e = 0; e < 8; ++e) a[e] += bf2f(uu[e]);
            }
            ushort8 o;
            #pragma unroll
            for (int e = 0; e < 8; ++e) o[e] = f2bf(a[e]);
            *(ushort8*)&SQ[ch * 8] = o;
            if (writeSt && h == 0)
                *(ushort8*)&StOut[(size_t)b * DD + ch * 8] = o;
            if (writeSrm && h == 0) {
                #pragma unroll
                for (int e = 0; e < 8; ++e) {
                    const int idx = ch * 8 + e;
                    const int rr = idx >> 7;
                    const int cc = (idx & 127) ^ ((rr & 7) << 3);
                    // element is S^T[rr][cc] = S[cc][rr] -> row-major at (cc, rr)
                    SrmOut[(size_t)b * DD + SW(cc, rr)] = o[e];
                }
            }
        }
    }
    __syncthreads();   // drains G/P asyncs; Sts visible

    // ---- (a) X' = Gf + S^T G : wave w = m-tiles {2w,2w+1} x 8 n-tiles ----
    f32x4 acc[2][8];
    const float* gf = Gf_in + (size_t)b * DD;
    #pragma unroll
    for (int m = 0; m < 2; ++m) {
        const int r0 = (w * 2 + m) * 16 + ((lane >> 4) << 2);
        #pragma unroll
        for (int nt = 0; nt < 8; ++nt) {
            const int cg = nt * 16 + (lane & 15);
            #pragma unroll
            for (int j = 0; j < 4; ++j) acc[m][nt][j] = gf[(size_t)(r0 + j) * 128 + cg];
        }
    }
    #pragma unroll
    for (int k0 = 0; k0 < 128; k0 += 32) {
        const bf16x8 a0 = fragAB(SQ, (w * 2 + 0) * 16, k0, lane);
        const bf16x8 a1 = fragAB(SQ, (w * 2 + 1) * 16, k0, lane);
        #pragma unroll
        for (int nt = 0; nt < 8; ++nt) {
            const bf16x8 bb = fragAB(Gs, nt * 16, k0, lane);
            acc[0][nt] = MFMA(a0, bb, acc[0][nt]);
            acc[1][nt] = MFMA(a1, bb, acc[1][nt]);
        }
    }
    // Xb = bf16(X') row-major swz
    #pragma unroll
    for (int m = 0; m < 2; ++m) {
        const int r0 = (w * 2 + m) * 16 + ((lane >> 4) << 2);
        #pragma unroll
        for (int nt = 0; nt < 8; ++nt) {
            const int cg = nt * 16 + (lane & 15);
            #pragma unroll
            for (int j = 0; j < 4; ++j) XU[SW(r0 + j, cg)] = f2bf(acc[m][nt][j]);
        }
    }
    __syncthreads();

    // ---- (b) G' = X' + X' S (C carried in regs, fp32) ----
    #pragma unroll
    for (int k0 = 0; k0 < 128; k0 += 32) {
        const bf16x8 a0 = fragAB(XU, (w * 2 + 0) * 16, k0, lane);
        const bf16x8 a1 = fragAB(XU, (w * 2 + 1) * 16, k0, lane);
        #pragma unroll
        for (int nt = 0; nt < 8; ++nt) {
            const bf16x8 bb = fragAB(SQ, nt * 16, k0, lane);
            acc[0][nt] = MFMA(a0, bb, acc[0][nt]);
            acc[1][nt] = MFMA(a1, bb, acc[1][nt]);
        }
    }
    __syncthreads();   // all waves done reading Gs(old)/Sts/Xb

    // Gs <- bf16(G') transposed-pack (symmetric); h==0 stores globals
    #pragma unroll
    for (int m = 0; m < 2; ++m) {
        const int rg0 = (w * 2 + m) * 16 + ((lane >> 4) << 2);
        #pragma unroll
        for (int nt = 0; nt < 8; ++nt) {
            const int cg = nt * 16 + (lane & 15);
            *(ushort4v*)&Gs[SW(cg, rg0)] = packbf(acc[m][nt]);
            if (h == 0) {
                *(f32x4*)&Gf_out[(size_t)b * DD + (size_t)cg * 128 + rg0] = acc[m][nt];
                *(ushort4v*)&Gbf_out[(size_t)b * DD + SW(cg, rg0)] = packbf(acc[m][nt]);
            }
        }
    }
    // issue Qs async into SQ (Sts fully consumed; Gs' writes pending in lgkm)
    {
        const unsigned short* qsrc = Qbl + (size_t)h * DD;
        #pragma unroll
        for (int i = 0; i < 8; ++i)
            async16((const char*)qsrc + (t + 256 * i) * 16, (char*)SQ + (t + 256 * i) * 16);
    }
    asm volatile("s_waitcnt lgkmcnt(0)" ::: "memory");
    __builtin_amdgcn_s_barrier();   // Gs' visible; Qs still in flight
    asm volatile("" ::: "memory");

    // ---- heads: U = G_l @ Pf^T ----
    f32x4 u[2][8] = {};
    #pragma unroll
    for (int k0 = 0; k0 < 128; k0 += 32) {
        const bf16x8 a0 = fragAB(Gs, (w * 2 + 0) * 16, k0, lane);
        const bf16x8 a1 = fragAB(Gs, (w * 2 + 1) * 16, k0, lane);
        #pragma unroll
        for (int i = 0; i < 8; ++i) {
            const bf16x8 bb = fragAB(Ps, i * 16, k0, lane);
            u[0][i] = MFMA(a0, bb, u[0][i]);
            u[1][i] = MFMA(a1, bb, u[1][i]);
        }
    }
    #pragma unroll
    for (int m = 0; m < 2; ++m) {
        const int rg0 = (w * 2 + m) * 16 + ((lane >> 4) << 2);
        #pragma unroll
        for (int i = 0; i < 8; ++i) {
            const int cg = i * 16 + (lane & 15);
            *(ushort4v*)&XU[SW(cg, rg0)] = packbf(u[m][i]);   // Ub = U^T
        }
    }
    asm volatile("s_waitcnt vmcnt(0) lgkmcnt(0)" ::: "memory");
    __builtin_amdgcn_s_barrier();   // Ub visible + Qs landed
    asm volatile("" ::: "memory");

    // ---- S_h = Qf @ U -> Spt_out ----
    f32x4 sv[2][8] = {};
    #pragma unroll
    for (int k0 = 0; k0 < 128; k0 += 32) {
        const bf16x8 a0 = fragAB(SQ, (w * 2 + 0) * 16, k0, lane);
        const bf16x8 a1 = fragAB(SQ, (w * 2 + 1) * 16, k0, lane);
        #pragma unroll
        for (int i = 0; i < 8; ++i) {
            const bf16x8 bb = fragAB(XU, i * 16, k0, lane);
            sv[0][i] = MFMA(a0, bb, sv[0][i]);
            sv[1][i] = MFMA(a1, bb, sv[1][i]);
        }
    }
    unsigned short* dst = Spt_out + (size_t)(b * H + h) * DD;
    #pragma unroll
    for (int m = 0; m < 2; ++m) {
        const int rg0 = (w * 2 + m) * 16 + ((lane >> 4) << 2);
        #pragma unroll
        for (int i = 0; i < 8; ++i) {
            const int cg = i * 16 + (lane & 15);
            *(ushort4v*)&dst[SW(cg, rg0)] = packbf(sv[m][i]);
        }
    }
}

// ---------------------------------------------------------------------------
// zfinal2: per block (redundant per-b): R-chain R_l^T = R^T + S_l^T + S_l^T R^T
// for l=1..3 (Rrm holds R row-major; step matmul A=St_l, B-frags=Rrm rows),
// then out = Z0 + Z0 @ R_3 (B-frags = R_3^T rows). grid (32, B) x 256.
// ---------------------------------------------------------------------------
__global__ __launch_bounds__(256) void zfinal2_kernel(
    const float* __restrict__ Zin, const unsigned short* __restrict__ Srm0,
    const unsigned short* __restrict__ St1, const unsigned short* __restrict__ St2,
    const unsigned short* __restrict__ Spt3, float* __restrict__ Zout)
{
    const int sblk = blockIdx.x, b = blockIdx.y;
    const int t = threadIdx.x, lane = t & 63, w = t >> 6;

    __shared__ __align__(16) float Zs[32 * 128];            // 16 KB
    __shared__ __align__(16) unsigned short Zb[32 * 128];   // 8 KB
    __shared__ __align__(16) unsigned short Rrm[DD];        // 32 KB: R row-major swz
    __shared__ __align__(16) unsigned short Stb[DD];        // 32 KB: S_l^T / finally R^T

    const float* zsrc = Zin + ((size_t)b * NP1 + sblk * 32) * D;
    #pragma unroll
    for (int i = 0; i < 4; ++i)
        async16(zsrc + (t + 256 * i) * 4, Zs + (t + 256 * i) * 4);
    #pragma unroll
    for (int i = 0; i < 8; ++i)
        async16((const char*)(Srm0 + (size_t)b * DD) + (t + 256 * i) * 16,
                (char*)Rrm + (t + 256 * i) * 16);
    #pragma unroll
    for (int i = 0; i < 8; ++i)
        async16((const char*)(St1 + (size_t)b * DD) + (t + 256 * i) * 16,
                (char*)Stb + (t + 256 * i) * 16);
    __syncthreads();

    // Zb = bf16(Z rows), swz (r11-proven)
    {
        const int r = t >> 3, c0 = (t & 7) * 16;
        const int sft = (r & 7) << 3;
        #pragma unroll
        for (int cc = 0; cc < 16; cc += 2) {
            const float v0 = Zs[r * 128 + c0 + cc];
            const float v1 = Zs[r * 128 + c0 + cc + 1];
            ((unsigned int*)Zb)[(r * 128 + ((c0 + cc) ^ sft)) >> 1] =
                (unsigned int)f2bf(v0) | ((unsigned int)f2bf(v1) << 16);
        }
    }
    __syncthreads();

    // ---- chain steps 1..3 ----
    #pragma unroll 1
    for (int step = 1; step <= 3; ++step) {
        // D = R_l^T: C-init = S^T[r,c] + R^T[r,c](=Rrm[c][r]); A = Stb, B = Rrm rows
        f32x4 racc[2][8];
        #pragma unroll
        for (int m = 0; m < 2; ++m) {
            const int r0 = (w * 2 + m) * 16 + ((lane >> 4) << 2);
            #pragma unroll
            for (int nt = 0; nt < 8; ++nt) {
                const int cg = nt * 16 + (lane & 15);
                #pragma unroll
                for (int j = 0; j < 4; ++j)
                    racc[m][nt][j] = bf2f(Stb[SW(r0 + j, cg)]) + bf2f(Rrm[SW(cg, r0 + j)]);
            }
        }
        #pragma unroll
        for (int k0 = 0; k0 < 128; k0 += 32) {
            const bf16x8 a0 = fragAB(Stb, (w * 2 + 0) * 16, k0, lane);
            const bf16x8 a1 = fragAB(Stb, (w * 2 + 1) * 16, k0, lane);
            #pragma unroll
            for (int nt = 0; nt < 8; ++nt) {
                const bf16x8 bb = fragAB(Rrm, nt * 16, k0, lane);
                racc[0][nt] = MFMA(a0, bb, racc[0][nt]);
                racc[1][nt] = MFMA(a1, bb, racc[1][nt]);
            }
        }
        __syncthreads();   // all reads of Rrm/Stb done

        if (step < 3) {
            // Rrm <- R_l row-major = tp-pack(D=R_l^T)
            #pragma unroll
            for (int m = 0; m < 2; ++m) {
                const int rg0 = (w * 2 + m) * 16 + ((lane >> 4) << 2);
                #pragma unroll
                for (int nt = 0; nt < 8; ++nt) {
                    const int cg = nt * 16 + (lane & 15);
                    *(ushort4v*)&Rrm[SW(cg, rg0)] = packbf(racc[m][nt]);
                }
            }
            // next S^T into Stb: step1 -> St2 (async); step2 -> reduce Spt3
            if (step == 1) {
                #pragma unroll
                for (int i = 0; i < 8; ++i)
                    async16((const char*)(St2 + (size_t)b * DD) + (t + 256 * i) * 16,
                            (char*)Stb + (t + 256 * i) * 16);
                asm volatile("s_waitcnt vmcnt(0) lgkmcnt(0)" ::: "memory");
                __builtin_amdgcn_s_barrier();
                asm volatile("" ::: "memory");
            } else {
                const unsigned short* sp0 = Spt3 + (size_t)b * H * DD;
                #pragma unroll 2
                for (int i = 0; i < 8; ++i) {
                    const int ch = t + 256 * i;
                    float a[8] = {0.f, 0.f, 0.f, 0.f, 0.f, 0.f, 0.f, 0.f};
                    #pragma unroll
                    for (int hh = 0; hh < 8; ++hh) {
                        const ushort8 uu = *(const ushort8*)&sp0[(size_t)hh * DD + ch * 8];
                        #pragma unroll
                        for (int e = 0; e < 8; ++e) a[e] += bf2f(uu[e]);
                    }
                    ushort8 o;
                    #pragma unroll
                    for (int e = 0; e < 8; ++e) o[e] = f2bf(a[e]);
                    *(ushort8*)&Stb[ch * 8] = o;
                }
                __syncthreads();
            }
        } else {
            // Stb <- R_3^T row-major (scatter; D IS R_3^T)
            #pragma unroll
            for (int m = 0; m < 2; ++m) {
                const int r0 = (w * 2 + m) * 16 + ((lane >> 4) << 2);
                #pragma unroll
                for (int nt = 0; nt < 8; ++nt) {
                    const int cg = nt * 16 + (lane & 15);
                    #pragma unroll
                    for (int j = 0; j < 4; ++j)
                        Stb[SW(r0 + j, cg)] = f2bf(racc[m][nt][j]);
                }
            }
            asm volatile("s_waitcnt lgkmcnt(0)" ::: "memory");
            __builtin_amdgcn_s_barrier();
            asm volatile("" ::: "memory");
        }
    }

    // ---- out = Z + Z @ R_3 (B-frags = Stb = R_3^T rows; r11-proven core) ----
    f32x4 accR[2][2] = {};
    #pragma unroll
    for (int k0 = 0; k0 < 128; k0 += 32) {
        const bf16x8 a0 = fragAB(Zb, 0, k0, lane);
        const bf16x8 a1 = fragAB(Zb, 16, k0, lane);
        const bf16x8 b0 = fragAB(Stb, (w * 2 + 0) * 16, k0, lane);
        const bf16x8 b1 = fragAB(Stb, (w * 2 + 1) * 16, k0, lane);
        accR[0][0] = MFMA(a0, b0, accR[0][0]);
        accR[0][1] = MFMA(a0, b1, accR[0][1]);
        accR[1][0] = MFMA(a1, b0, accR[1][0]);
        accR[1][1] = MFMA(a1, b1, accR[1][1]);
    }
    #pragma unroll
    for (int m = 0; m < 2; ++m) {
        const int r0 = m * 16 + ((lane >> 4) << 2);
        #pragma unroll
        for (int nl = 0; nl < 2; ++nl) {
            const int cc = (w * 2 + nl) * 16 + (lane & 15);
            #pragma unroll
            for (int j = 0; j < 4; ++j) {
                const int r = r0 + j;
                Zout[((size_t)b * NP1 + sblk * 32 + r) * D + cc] =
                    Zs[r * 128 + cc] + accR[m][nl][j];
            }
        }
    }
}

// ---------------------------------------------------------------------------
extern "C" void kernel_launch(void* const* d_in, const int* in_sizes, int n_in,
                              void* d_out, int out_size, void* d_ws, size_t ws_size,
                              hipStream_t stream)
{
    const float* Z0 = (const float*)d_in[0];
    const float* ap = (const float*)d_in[1];
    float* out = (float*)d_out;
    float* ws  = (float*)d_ws;

    float* Gp  = ws + WS_GP;
    unsigned short* Spt = (unsigned short*)(ws + WS_SPT);   // [2][B][H][DD]
    unsigned short* Qb  = (unsigned short*)(ws + WS_QB);
    unsigned short* Pb  = (unsigned short*)(ws + WS_PB);
    unsigned short* Gbf = (unsigned short*)(ws + WS_GBF);   // [2][B][DD]
    float* Gf           = ws + WS_GF;                       // [2][B][DD]
    unsigned short* Srm = (unsigned short*)(ws + WS_SRM);
    unsigned short* St1 = (unsigned short*)(ws + WS_ST1);
    unsigned short* St2 = (unsigned short*)(ws + WS_ST2);

    hipLaunchKernelGGL(pg_kernel,   dim3(192),   dim3(256), 0, stream, Z0, Gp, ap, Qb, Pb);
    hipLaunchKernelGGL(gred_kernel, dim3(16, B), dim3(256), 0, stream, Gp, Gbf, Gf);
    hipLaunchKernelGGL(heads0_kernel, dim3(H, B), dim3(256), 0, stream, Qb, Pb, Gbf, Spt);

    for (int l = 1; l < NL; ++l) {
        const int gi = (l + 1) & 1, go = l & 1;     // G slots: gred wrote 0; l=1 reads 0
        const int si = (l - 1) & 1, so = l & 1;     // Spt slots: heads0 wrote 0
        hipLaunchKernelGGL(headsu_kernel, dim3(H, B), dim3(256), 0, stream,
                           Qb + (size_t)l * H * DD, Pb + (size_t)l * H * DD,
                           Gbf + (size_t)gi * B * DD, Gf + (size_t)gi * B * DD,
                           Gbf + (size_t)go * B * DD, Gf + (size_t)go * B * DD,
                           Spt + (size_t)si * B * H * DD, Spt + (size_t)so * B * H * DD,
                           (l == 2) ? St1 : St2, Srm,
                           (l >= 2) ? 1 : 0, (l == 1) ? 1 : 0);
    }

    hipLaunchKernelGGL(zfinal2_kernel, dim3(32, B), dim3(256), 0, stream,
                       Z0, Srm, St1, St2, Spt + (size_t)1 * B * H * DD, out);
}

// Round 13
// 140.339 us; speedup vs baseline: 1.1291x; 1.1291x over previous
//
#include <hip/hip_runtime.h>

// Problem constants
#define D    128      // d+1
#define DM   127      // d
#define NP1  1024     // N+1
#define B    8
#define H    8
#define NL   4

typedef __attribute__((ext_vector_type(8))) __bf16 bf16x8;
typedef __attribute__((ext_vector_type(8))) unsigned short ushort8;
typedef __attribute__((ext_vector_type(4))) unsigned short ushort4v;
typedef __attribute__((ext_vector_type(4))) float f32x4;

// Workspace layout (float offsets). ~14.5 MB total.
#define WS_GP  0                        // [B][8][128][128] f32 Gram partials (symmetric)
#define WS_SPT (WS_GP + B*8*D*D)        // [B][H][128][128] f32 Sp TRANSPOSED
#define WS_QB  (WS_SPT + B*H*D*D)       // [NL][H][128][128] bf16 Q*(1/N), swizzled
#define WS_PB  (WS_QB + NL*H*D*D/2)     // [NL][H][128][128] bf16 P padded (+corner 1), swizzled
#define WS_GB  (WS_PB + NL*H*D*D/2)     // [B][128][128] bf16 G, swizzled
#define WS_ST  (WS_GB + B*D*D/2)        // [B][128][128] bf16 S^T, swizzled
#define WS_ZT  (WS_ST + B*D*D/2)        // [B][8][128][128] bf16 Z^T per chunk, swizzled, tok1023-masked

// Async global->LDS, 16B/lane (dest = wave-uniform base + lane*16; linear).
__device__ __forceinline__ void async16(const void* g, void* l)
{
    __builtin_amdgcn_global_load_lds(
        (const __attribute__((address_space(1))) void*)g,
        (__attribute__((address_space(3))) void*)l,
        16, 0, 0);
}

// fp32 -> bf16 round-to-nearest-even
__device__ __forceinline__ unsigned short f2bf(float f)
{
    unsigned int u = __float_as_uint(f);
    u += 0x7fffu + ((u >> 16) & 1u);
    return (unsigned short)(u >> 16);
}

// Swizzled elem index for bf16 [*][128] row-major tiles: col ^= (row&7)<<3.
__device__ __forceinline__ int SW(int row, int col)
{
    return row * 128 + (col ^ ((row & 7) << 3));
}

// A/B fragment from a swizzled bf16 LDS tile: lane supplies matrix row
// row0+(l&15), k = k0 + (l>>4)*8 + j. k-enumeration cancels between A and B.
__device__ __forceinline__ bf16x8 fragAB(const unsigned short* Lb, int row0, int k0, int lane)
{
    const int r = row0 + (lane & 15);
    const int c = (k0 + ((lane >> 4) << 3)) ^ ((r & 7) << 3);
    union { ushort8 u; bf16x8 b; } U;
    U.u = *(const ushort8*)&Lb[r * 128 + c];
    return U.b;
}

#define MFMA(a, b, c) __builtin_amdgcn_mfma_f32_16x16x32_bf16((a), (b), (c), 0, 0, 0)

// ---------------------------------------------------------------------------
// init (once, merged prologue): blocks 0..63 = ztr0 (Ztr from Z0, r10-proven);
// blocks 64..191 = prep (params -> bf16 swz, r9-proven). grid 192 x 256.
// ---------------------------------------------------------------------------
__global__ __launch_bounds__(256) void init_kernel(
    const float* __restrict__ Z, unsigned short* __restrict__ Ztr,
    const float* __restrict__ ap, unsigned short* __restrict__ Qb,
    unsigned short* __restrict__ Pb)
{
    const int t = threadIdx.x;
    __shared__ __align__(16) float Zs[128 * 128];          // 64 KB
    __shared__ __align__(16) unsigned short Zt[128 * 128]; // 32 KB

    if (blockIdx.x < 64) {
        const int c = blockIdx.x & 7, b = blockIdx.x >> 3;

        const float* src = Z + ((size_t)b * NP1 + c * 128) * D;
        #pragma unroll
        for (int i = 0; i < 16; ++i)
            async16(src + (t + 256 * i) * 4, Zs + (t + 256 * i) * 4);
        __syncthreads();

        {
            const int d = t >> 1, half = t & 1;
            const int sft = (d & 7) << 3;
            #pragma unroll 4
            for (int tp = 0; tp < 32; ++tp) {
                const int tk = ((tp + d) & 31) * 2 + half * 64;
                float v0 = Zs[tk * 128 + d];
                float v1 = Zs[(tk + 1) * 128 + d];
                if (c == 7 && tk == 126) v1 = 0.f;   // key mask: token 1023
                ((unsigned int*)Zt)[(d * 128 + (tk ^ sft)) >> 1] =
                    (unsigned int)f2bf(v0) | ((unsigned int)f2bf(v1) << 16);
            }
        }
        __syncthreads();

        ushort8* dst = (ushort8*)(Ztr + (size_t)(b * 8 + c) * D * D);
        #pragma unroll
        for (int i = 0; i < 8; ++i)
            dst[t + 256 * i] = ((const ushort8*)Zt)[t + 256 * i];
    } else {
        const int pid = blockIdx.x - 64;   // 0..127
        const float inv = 1.0f / 1023.0f;
        #pragma unroll
        for (int e = 0; e < 16; ++e) {
            const int p  = pid * 4096 + e * 256 + t;   // 0 .. 2^19-1
            const int c  = (p & 63) * 2;
            const int r  = (p >> 6) & 127;
            const int h  = (p >> 13) & 7;
            const int isP = (p >> 16) & 1;
            const int l  = (p >> 17) & 3;
            const float* apl = ap + ((size_t)(l * H + h) * 2 + (isP ? 0 : 1)) * DM * DM;
            float v0, v1;
            if (!isP) {
                v0 = (r < DM && c     < DM) ? apl[r * DM + c] * inv     : 0.f;
                v1 = (r < DM && c + 1 < DM) ? apl[r * DM + c + 1] * inv : 0.f;
            } else {
                v0 = (r < DM && c     < DM) ? apl[r * DM + c]     : 0.f;
                v1 = (r < DM && c + 1 < DM) ? apl[r * DM + c + 1]
                     : ((r == DM && c + 1 == DM) ? 1.f : 0.f);
            }
            unsigned short* base = (isP ? Pb : Qb) + (size_t)(l * H + h) * D * D;
            const int el = SW(r, c);
            ((unsigned int*)base)[el >> 1] =
                (unsigned int)f2bf(v0) | ((unsigned int)f2bf(v1) << 16);
        }
    }
}

// ---------------------------------------------------------------------------
// gp: Gram partial of chunk c via MFMA, directly from bf16 Ztr.
// grid (8 chunks, 4 n-quarters, B) = 256 blocks x 256. LDS = 32 KB. (r10-proven)
// ---------------------------------------------------------------------------
__global__ __launch_bounds__(256) void gp_kernel(
    const unsigned short* __restrict__ Ztr, float* __restrict__ Gp)
{
    const int c = blockIdx.x, q = blockIdx.y, b = blockIdx.z;
    const int t = threadIdx.x, lane = t & 63, w = t >> 6;

    __shared__ __align__(16) unsigned short Zt[128 * 128]; // 32 KB

    const unsigned short* src = Ztr + (size_t)(b * 8 + c) * D * D;
    #pragma unroll
    for (int i = 0; i < 8; ++i)
        async16((const char*)src + (t + 256 * i) * 16, (char*)Zt + (t + 256 * i) * 16);
    __syncthreads();

    f32x4 acc[2][2] = {};
    #pragma unroll
    for (int k0 = 0; k0 < 128; k0 += 32) {
        const bf16x8 a0 = fragAB(Zt, (w * 2 + 0) * 16, k0, lane);
        const bf16x8 a1 = fragAB(Zt, (w * 2 + 1) * 16, k0, lane);
        const bf16x8 b0 = fragAB(Zt, q * 32,      k0, lane);
        const bf16x8 b1 = fragAB(Zt, q * 32 + 16, k0, lane);
        acc[0][0] = MFMA(a0, b0, acc[0][0]);
        acc[0][1] = MFMA(a0, b1, acc[0][1]);
        acc[1][0] = MFMA(a1, b0, acc[1][0]);
        acc[1][1] = MFMA(a1, b1, acc[1][1]);
    }

    float* Gb = Gp + ((size_t)(b * 8 + c)) * D * D;
    #pragma unroll
    for (int m = 0; m < 2; ++m) {
        const int rg = (w * 2 + m) * 16 + ((lane >> 4) << 2);
        #pragma unroll
        for (int nl = 0; nl < 2; ++nl) {
            const int cg = q * 32 + nl * 16 + (lane & 15);
            *(f32x4*)&Gb[cg * 128 + rg] = acc[m][nl];   // transposed store (symmetric)
        }
    }
}

// ---------------------------------------------------------------------------
// gred: G[b] = sum_c Gp[b][c] -> bf16 swizzled. grid (16, B) x 256. (proven)
// ---------------------------------------------------------------------------
__global__ __launch_bounds__(256) void gred_kernel(
    const float* __restrict__ Gp, unsigned short* __restrict__ Gbf)
{
    const int b = blockIdx.y;
    const int idx4 = blockIdx.x * 256 + threadIdx.x;   // 0..4095
    float4 sum = make_float4(0.f, 0.f, 0.f, 0.f);
    #pragma unroll
    for (int c = 0; c < 8; ++c) {
        const float4 v = ((const float4*)Gp)[(size_t)(b * 8 + c) * 4096 + idx4];
        sum.x += v.x; sum.y += v.y; sum.z += v.z; sum.w += v.w;
    }
    const int row = idx4 >> 5;
    const int n0  = (idx4 & 31) * 4;
    const int el  = SW(row, n0);
    unsigned int* dst = (unsigned int*)(Gbf + (size_t)b * D * D);
    dst[(el >> 1) + 0] = (unsigned int)f2bf(sum.x) | ((unsigned int)f2bf(sum.y) << 16);
    dst[(el >> 1) + 1] = (unsigned int)f2bf(sum.z) | ((unsigned int)f2bf(sum.w) << 16);
}

// ---------------------------------------------------------------------------
// ts: T = Qf_h @ G_b; Spt = (T @ P_h^T)^T. grid (4, H, B) x 256. (proven)
// ---------------------------------------------------------------------------
__global__ __launch_bounds__(256) void ts_kernel(
    const unsigned short* __restrict__ Qb, const unsigned short* __restrict__ Pb,
    const unsigned short* __restrict__ Gbf, float* __restrict__ Spt)
{
    const int s = blockIdx.x, h = blockIdx.y, b = blockIdx.z;
    const int t = threadIdx.x, lane = t & 63, w = t >> 6;

    __shared__ __align__(16) unsigned short Qs[32 * 128];   // 8 KB
    __shared__ __align__(16) unsigned short Gs[128 * 128];  // 32 KB
    __shared__ __align__(16) unsigned short Ps[128 * 128];  // 32 KB
    __shared__ __align__(16) unsigned short Tb[32 * 128];   // 8 KB

    const unsigned short* qsrc = Qb + (size_t)h * D * D + s * 32 * 128;
    #pragma unroll
    for (int i = 0; i < 2; ++i)
        async16((const char*)qsrc + (t + 256 * i) * 16, (char*)Qs + (t + 256 * i) * 16);
    const unsigned short* gsrc = Gbf + (size_t)b * D * D;
    #pragma unroll
    for (int i = 0; i < 8; ++i)
        async16((const char*)gsrc + (t + 256 * i) * 16, (char*)Gs + (t + 256 * i) * 16);
    const unsigned short* psrc = Pb + (size_t)h * D * D;
    #pragma unroll
    for (int i = 0; i < 8; ++i)
        async16((const char*)psrc + (t + 256 * i) * 16, (char*)Ps + (t + 256 * i) * 16);

    // wait for Q+G; Ps's 8 loads stay in flight under phase 1
    asm volatile("s_waitcnt vmcnt(8)" ::: "memory");
    __builtin_amdgcn_s_barrier();
    asm volatile("" ::: "memory");

    f32x4 accT[2][2] = {};
    #pragma unroll
    for (int k0 = 0; k0 < 128; k0 += 32) {
        const bf16x8 a0 = fragAB(Qs, 0, k0, lane);
        const bf16x8 a1 = fragAB(Qs, 16, k0, lane);
        const bf16x8 b0 = fragAB(Gs, (w * 2 + 0) * 16, k0, lane);
        const bf16x8 b1 = fragAB(Gs, (w * 2 + 1) * 16, k0, lane);
        accT[0][0] = MFMA(a0, b0, accT[0][0]);
        accT[0][1] = MFMA(a0, b1, accT[0][1]);
        accT[1][0] = MFMA(a1, b0, accT[1][0]);
        accT[1][1] = MFMA(a1, b1, accT[1][1]);
    }
    #pragma unroll
    for (int m = 0; m < 2; ++m) {
        #pragma unroll
        for (int nl = 0; nl < 2; ++nl) {
            const int cc = (w * 2 + nl) * 16 + (lane & 15);
            const int r0 = m * 16 + ((lane >> 4) << 2);
            #pragma unroll
            for (int j = 0; j < 4; ++j)
                Tb[SW(r0 + j, cc)] = f2bf(accT[m][nl][j]);
        }
    }
    __syncthreads();   // T visible; drains Ps loads

    f32x4 accS[2][2] = {};
    #pragma unroll
    for (int k0 = 0; k0 < 128; k0 += 32) {
        const bf16x8 a0 = fragAB(Tb, 0, k0, lane);
        const bf16x8 a1 = fragAB(Tb, 16, k0, lane);
        const bf16x8 b0 = fragAB(Ps, (w * 2 + 0) * 16, k0, lane);
        const bf16x8 b1 = fragAB(Ps, (w * 2 + 1) * 16, k0, lane);
        accS[0][0] = MFMA(a0, b0, accS[0][0]);
        accS[0][1] = MFMA(a0, b1, accS[0][1]);
        accS[1][0] = MFMA(a1, b0, accS[1][0]);
        accS[1][1] = MFMA(a1, b1, accS[1][1]);
    }

    float* SptBH = Spt + (size_t)(b * 8 + h) * D * D;
    #pragma unroll
    for (int m = 0; m < 2; ++m) {
        const int rg = s * 32 + m * 16 + ((lane >> 4) << 2);
        #pragma unroll
        for (int nl = 0; nl < 2; ++nl) {
            const int cg = (w * 2 + nl) * 16 + (lane & 15);
            *(f32x4*)&SptBH[cg * 128 + rg] = accS[m][nl];
        }
    }
}

// ---------------------------------------------------------------------------
// sred: St = bf16( sum_h Spt[b][h] ), swizzled. grid (16, B) x 256. (proven)
// ---------------------------------------------------------------------------
__global__ __launch_bounds__(256) void sred_kernel(
    const float* __restrict__ Spt, unsigned short* __restrict__ St)
{
    const int b = blockIdx.y;
    const int idx4 = blockIdx.x * 256 + threadIdx.x;
    float4 sum = make_float4(0.f, 0.f, 0.f, 0.f);
    #pragma unroll
    for (int h = 0; h < 8; ++h) {
        const float4 v = ((const float4*)Spt)[(size_t)(b * 8 + h) * 4096 + idx4];
        sum.x += v.x; sum.y += v.y; sum.z += v.z; sum.w += v.w;
    }
    const int row = idx4 >> 5;
    const int k0  = (idx4 & 31) * 4;
    const int el  = SW(row, k0);
    unsigned int* dst = (unsigned int*)(St + (size_t)b * D * D);
    dst[(el >> 1) + 0] = (unsigned int)f2bf(sum.x) | ((unsigned int)f2bf(sum.y) << 16);
    dst[(el >> 1) + 1] = (unsigned int)f2bf(sum.z) | ((unsigned int)f2bf(sum.w) << 16);
}

// ---------------------------------------------------------------------------
// z: out = Z + Z @ S via MFMA; also emits next layer's Ztr (bf16 transposed
// swizzled, token-1023-masked) straight from the epilogue registers.
// grid (32, B) x 256. LDS = 56 KB. (r10-proven)
// ---------------------------------------------------------------------------
__global__ __launch_bounds__(256) void z_kernel(
    const float* __restrict__ Zin, const unsigned short* __restrict__ St,
    float* __restrict__ Zout, unsigned short* __restrict__ Ztr, int writeZtr)
{
    const int sblk = blockIdx.x, b = blockIdx.y;
    const int t = threadIdx.x, lane = t & 63, w = t >> 6;

    __shared__ __align__(16) float Zs[32 * 128];            // 16 KB fp32 staging
    __shared__ __align__(16) unsigned short Zb[32 * 128];   // 8 KB bf16 swizzled
    __shared__ __align__(16) unsigned short Ss[128 * 128];  // 32 KB bf16 swizzled (S^T)

    const float* zsrc = Zin + ((size_t)b * NP1 + sblk * 32) * D;
    #pragma unroll
    for (int i = 0; i < 4; ++i)
        async16(zsrc + (t + 256 * i) * 4, Zs + (t + 256 * i) * 4);
    const unsigned short* ssrc = St + (size_t)b * D * D;
    #pragma unroll
    for (int i = 0; i < 8; ++i)
        async16((const char*)ssrc + (t + 256 * i) * 16, (char*)Ss + (t + 256 * i) * 16);

    asm volatile("s_waitcnt vmcnt(8)" ::: "memory");
    __builtin_amdgcn_s_barrier();
    asm volatile("" ::: "memory");

    {
        const int r = t >> 3, c0 = (t & 7) * 16;
        const int sft = (r & 7) << 3;
        #pragma unroll
        for (int cc = 0; cc < 16; cc += 2) {
            const float v0 = Zs[r * 128 + c0 + cc];
            const float v1 = Zs[r * 128 + c0 + cc + 1];
            ((unsigned int*)Zb)[(r * 128 + ((c0 + cc) ^ sft)) >> 1] =
                (unsigned int)f2bf(v0) | ((unsigned int)f2bf(v1) << 16);
        }
    }
    __syncthreads();   // Zb visible; drains Ss loads

    f32x4 accR[2][2] = {};
    #pragma unroll
    for (int k0 = 0; k0 < 128; k0 += 32) {
        const bf16x8 a0 = fragAB(Zb, 0, k0, lane);
        const bf16x8 a1 = fragAB(Zb, 16, k0, lane);
        const bf16x8 b0 = fragAB(Ss, (w * 2 + 0) * 16, k0, lane);
        const bf16x8 b1 = fragAB(Ss, (w * 2 + 1) * 16, k0, lane);
        accR[0][0] = MFMA(a0, b0, accR[0][0]);
        accR[0][1] = MFMA(a0, b1, accR[0][1]);
        accR[1][0] = MFMA(a1, b0, accR[1][0]);
        accR[1][1] = MFMA(a1, b1, accR[1][1]);
    }

    // epilogue: out = Zs + res; optional transposed bf16 emit for next gp
    #pragma unroll
    for (int m = 0; m < 2; ++m) {
        const int r0 = m * 16 + ((lane >> 4) << 2);
        #pragma unroll
        for (int nl = 0; nl < 2; ++nl) {
            const int cc = (w * 2 + nl) * 16 + (lane & 15);
            float o[4];
            #pragma unroll
            for (int j = 0; j < 4; ++j) {
                const int r = r0 + j;
                o[j] = Zs[r * 128 + cc] + accR[m][nl][j];
                Zout[((size_t)b * NP1 + sblk * 32 + r) * D + cc] = o[j];
            }
            if (writeZtr) {
                const int gt0   = sblk * 32 + r0;       // global token of j=0
                const int chunk = gt0 >> 7;
                const int tok0  = gt0 & 127;            // 4-aligned -> 8B run contiguous under SW
                ushort4v v;
                #pragma unroll
                for (int j = 0; j < 4; ++j)
                    v[j] = (gt0 + j == 1023) ? (unsigned short)0 : f2bf(o[j]);
                unsigned short* tile = Ztr + (size_t)(b * 8 + chunk) * D * D;
                *(ushort4v*)&tile[SW(cc, tok0)] = v;
            }
        }
    }
}

// ---------------------------------------------------------------------------
extern "C" void kernel_launch(void* const* d_in, const int* in_sizes, int n_in,
                              void* d_out, int out_size, void* d_ws, size_t ws_size,
                              hipStream_t stream)
{
    const float* Z0 = (const float*)d_in[0];
    const float* ap = (const float*)d_in[1];
    float* out = (float*)d_out;
    float* ws  = (float*)d_ws;

    float* Gp  = ws + WS_GP;
    float* Spt = ws + WS_SPT;
    unsigned short* Qb  = (unsigned short*)(ws + WS_QB);
    unsigned short* Pb  = (unsigned short*)(ws + WS_PB);
    unsigned short* Gbf = (unsigned short*)(ws + WS_GB);
    unsigned short* St  = (unsigned short*)(ws + WS_ST);
    unsigned short* Ztr = (unsigned short*)(ws + WS_ZT);

    hipLaunchKernelGGL(init_kernel, dim3(192), dim3(256), 0, stream, Z0, Ztr, ap, Qb, Pb);

    const float* Zcur = Z0;
    for (int l = 0; l < NL; ++l) {
        const unsigned short* Qbl = Qb + (size_t)l * H * D * D;
        const unsigned short* Pbl = Pb + (size_t)l * H * D * D;
        hipLaunchKernelGGL(gp_kernel,   dim3(8, 4, B), dim3(256), 0, stream, Ztr, Gp);
        hipLaunchKernelGGL(gred_kernel, dim3(16, B),   dim3(256), 0, stream, Gp, Gbf);
        hipLaunchKernelGGL(ts_kernel,   dim3(4, H, B), dim3(256), 0, stream, Qbl, Pbl, Gbf, Spt);
        hipLaunchKernelGGL(sred_kernel, dim3(16, B),   dim3(256), 0, stream, Spt, St);
        hipLaunchKernelGGL(z_kernel,    dim3(32, B),   dim3(256), 0, stream,
                           Zcur, St, out, Ztr, (l < NL - 1) ? 1 : 0);
        Zcur = out;
    }
}